// Round 6
// baseline (273.468 us; speedup 1.0000x reference)
//
#include <hip/hip_runtime.h>
#include <math.h>

#define B_   32
#define S_   4
#define H_   16
#define D_   64
#define E_   1024
#define KV_  4096
#define NBH  512            // B_*H_
#define CS   512            // cached rows per chunk
#define NC   9              // 8 cache chunks + 1 "new rows" chunk
#define RECSZ 264           // 4 m + 4 l + 256 O floats per partial record

// ---------------------------------------------------------------------------
// Shared GEMM core: A[4][1024] (LDS) x W rows [n0..n0+63] -> res[256].
// kk-hoisted: A fragments read ONCE per kk and reused across 4 W-row groups
// (64 ds_read_b128/thread instead of 256). 4 concurrent global W streams.
// ---------------------------------------------------------------------------
__device__ __forceinline__ void gemm_core(const float* __restrict__ a_lds,
                                          const float* __restrict__ W,
                                          int n0, int tid,
                                          float* __restrict__ res) {
    const int lane = tid & 63, wid = tid >> 6;
    const int sub = lane >> 4, cg = lane & 15, tsel = cg & 3;

    float acc[4][4];                      // [g][token]
    #pragma unroll
    for (int g = 0; g < 4; ++g)
        #pragma unroll
        for (int t = 0; t < 4; ++t) acc[g][t] = 0.f;

    const float4* wr0 = (const float4*)(W + (size_t)(n0 + wid * 16 + 0) * E_);
    const float4* wr1 = (const float4*)(W + (size_t)(n0 + wid * 16 + 4) * E_);
    const float4* wr2 = (const float4*)(W + (size_t)(n0 + wid * 16 + 8) * E_);
    const float4* wr3 = (const float4*)(W + (size_t)(n0 + wid * 16 + 12) * E_);

    #pragma unroll
    for (int kk = 0; kk < 16; ++kk) {
        const float4 a0 = *(const float4*)&a_lds[0 * E_ + kk * 64 + cg * 4];
        const float4 a1 = *(const float4*)&a_lds[1 * E_ + kk * 64 + cg * 4];
        const float4 a2 = *(const float4*)&a_lds[2 * E_ + kk * 64 + cg * 4];
        const float4 a3 = *(const float4*)&a_lds[3 * E_ + kk * 64 + cg * 4];
        const int wi = sub * 256 + kk * 16 + cg;
        float4 w;
        w = wr0[wi];
        acc[0][0] += w.x*a0.x + w.y*a0.y + w.z*a0.z + w.w*a0.w;
        acc[0][1] += w.x*a1.x + w.y*a1.y + w.z*a1.z + w.w*a1.w;
        acc[0][2] += w.x*a2.x + w.y*a2.y + w.z*a2.z + w.w*a2.w;
        acc[0][3] += w.x*a3.x + w.y*a3.y + w.z*a3.z + w.w*a3.w;
        w = wr1[wi];
        acc[1][0] += w.x*a0.x + w.y*a0.y + w.z*a0.z + w.w*a0.w;
        acc[1][1] += w.x*a1.x + w.y*a1.y + w.z*a1.z + w.w*a1.w;
        acc[1][2] += w.x*a2.x + w.y*a2.y + w.z*a2.z + w.w*a2.w;
        acc[1][3] += w.x*a3.x + w.y*a3.y + w.z*a3.z + w.w*a3.w;
        w = wr2[wi];
        acc[2][0] += w.x*a0.x + w.y*a0.y + w.z*a0.z + w.w*a0.w;
        acc[2][1] += w.x*a1.x + w.y*a1.y + w.z*a1.z + w.w*a1.w;
        acc[2][2] += w.x*a2.x + w.y*a2.y + w.z*a2.z + w.w*a2.w;
        acc[2][3] += w.x*a3.x + w.y*a3.y + w.z*a3.z + w.w*a3.w;
        w = wr3[wi];
        acc[3][0] += w.x*a0.x + w.y*a0.y + w.z*a0.z + w.w*a0.w;
        acc[3][1] += w.x*a1.x + w.y*a1.y + w.z*a1.z + w.w*a1.w;
        acc[3][2] += w.x*a2.x + w.y*a2.y + w.z*a2.z + w.w*a2.w;
        acc[3][3] += w.x*a3.x + w.y*a3.y + w.z*a3.z + w.w*a3.w;
    }

    #pragma unroll
    for (int g = 0; g < 4; ++g) {
        float ac0 = acc[g][0], ac1 = acc[g][1], ac2 = acc[g][2], ac3 = acc[g][3];
        ac0 += __shfl_xor(ac0, 1); ac0 += __shfl_xor(ac0, 2);
        ac1 += __shfl_xor(ac1, 1); ac1 += __shfl_xor(ac1, 2);
        ac2 += __shfl_xor(ac2, 1); ac2 += __shfl_xor(ac2, 2);
        ac3 += __shfl_xor(ac3, 1); ac3 += __shfl_xor(ac3, 2);
        float v = (tsel & 1) ? ((tsel & 2) ? ac3 : ac1)
                             : ((tsel & 2) ? ac2 : ac0);
        v += __shfl_xor(v, 4); v += __shfl_xor(v, 8);
        if (cg < 4) res[cg * 64 + (wid * 16 + g * 4 + sub)] = v;
    }
}

// ---------------------------------------------------------------------------
// Fused Q/K/V projection. grid (32, 16, 3), block 256.
// z selects {Wq,Wk,Wv}; output scattered to [b,h,s,d] at outbase + z*131072.
// ---------------------------------------------------------------------------
__global__ __launch_bounds__(256) void proj_qkv_kernel(
    const float* __restrict__ x,
    const float* __restrict__ Wq, const float* __restrict__ bq,
    const float* __restrict__ Wk, const float* __restrict__ bk,
    const float* __restrict__ Wv, const float* __restrict__ bv,
    float* __restrict__ outbase) {
    __shared__ float a_lds[4 * E_];
    __shared__ float res[256];
    const int t0 = blockIdx.x * 4;
    const int n0 = blockIdx.y * 64;
    const int z = blockIdx.z;
    const int tid = threadIdx.x;

    const float* W    = (z == 0) ? Wq : (z == 1) ? Wk : Wv;
    const float* bias = (z == 0) ? bq : (z == 1) ? bk : bv;
    float* out = outbase + (size_t)z * (B_ * S_ * E_);

    const float4* Ag = (const float4*)(x + (size_t)t0 * E_);
    float4* al = (float4*)a_lds;
    #pragma unroll
    for (int i = 0; i < 4; ++i) al[tid + 256 * i] = Ag[tid + 256 * i];
    __syncthreads();

    gemm_core(a_lds, W, n0, tid, res);
    __syncthreads();

    const float val = res[tid] + bias[n0 + (tid & 63)];
    const int t = t0 + (tid >> 6), e = n0 + (tid & 63);
    const int b = t >> 2, s = t & 3, h = e >> 6, dk = e & 63;
    out[((size_t)((b * H_ + h) * S_ + s)) * D_ + dk] = val;
}

// ---------------------------------------------------------------------------
// Attention partials: single-pass flash decoding, 8 rows/wave/iteration
// (byte-identical structure to round 5 — verified).
// ---------------------------------------------------------------------------
__device__ __forceinline__ float wave_max64(float v) {
    #pragma unroll
    for (int off = 32; off > 0; off >>= 1) v = fmaxf(v, __shfl_xor(v, off));
    return v;
}

__global__ __launch_bounds__(256) void attn_partial_kernel(
    const float* __restrict__ Qw, const float* __restrict__ Kc,
    const float* __restrict__ Vc, const float* __restrict__ Kn,
    const float* __restrict__ Vn, float* __restrict__ part) {
    __shared__ float q_s[S_ * D_];
    __shared__ float ob[4][256];
    __shared__ float mw[4];
    __shared__ float lw[4][4];

    const int bh = blockIdx.x;
    const int c = blockIdx.y;
    const int tid = threadIdx.x;
    const int lane = tid & 63, wid = tid >> 6;
    const int sub = lane >> 4, cg = lane & 15, qsel = cg & 3;

    q_s[tid] = Qw[(size_t)bh * 256 + tid];
    __syncthreads();

    const float* kptr;
    const float* vptr;
    int nrows;
    if (c < 8) {
        kptr = Kc + ((size_t)bh * KV_ + c * CS) * D_;
        vptr = Vc + ((size_t)bh * KV_ + c * CS) * D_;
        nrows = CS;
    } else {
        kptr = Kn + (size_t)bh * 256;
        vptr = Vn + (size_t)bh * 256;
        nrows = S_;
    }

    const float4 q0 = *(const float4*)&q_s[0 * 64 + cg * 4];
    const float4 q1 = *(const float4*)&q_s[1 * 64 + cg * 4];
    const float4 q2 = *(const float4*)&q_s[2 * 64 + cg * 4];
    const float4 q3 = *(const float4*)&q_s[3 * 64 + cg * 4];

    const float4 z4 = make_float4(0.f, 0.f, 0.f, 0.f);
    float m_run = -INFINITY;
    float l_run = 0.f;
    float4 a0 = z4, a1 = z4, a2 = z4, a3 = z4;

    int r0 = wid * 8;
    float4 kvA = z4, vvA = z4, kvB = z4, vvB = z4;
    bool vB = false;
    if (r0 < nrows) {
        kvA = ((const float4*)(kptr + (size_t)r0 * D_))[lane];
        vvA = ((const float4*)(vptr + (size_t)r0 * D_))[lane];
        if (r0 + 4 < nrows) {
            vB = true;
            kvB = ((const float4*)(kptr + (size_t)(r0 + 4) * D_))[lane];
            vvB = ((const float4*)(vptr + (size_t)(r0 + 4) * D_))[lane];
        }
    }

    while (r0 < nrows) {
        const int rn = r0 + 32;
        float4 nkA = z4, nvA = z4, nkB = z4, nvB = z4;
        bool vBn = false;
        if (rn < nrows) {                        // prefetch next 8-row group
            nkA = ((const float4*)(kptr + (size_t)rn * D_))[lane];
            nvA = ((const float4*)(vptr + (size_t)rn * D_))[lane];
            if (rn + 4 < nrows) {
                vBn = true;
                nkB = ((const float4*)(kptr + (size_t)(rn + 4) * D_))[lane];
                nvB = ((const float4*)(vptr + (size_t)(rn + 4) * D_))[lane];
            }
        }

        float pA0 = kvA.x * q0.x + kvA.y * q0.y + kvA.z * q0.z + kvA.w * q0.w;
        float pA1 = kvA.x * q1.x + kvA.y * q1.y + kvA.z * q1.z + kvA.w * q1.w;
        float pA2 = kvA.x * q2.x + kvA.y * q2.y + kvA.z * q2.z + kvA.w * q2.w;
        float pA3 = kvA.x * q3.x + kvA.y * q3.y + kvA.z * q3.z + kvA.w * q3.w;
        float pB0 = kvB.x * q0.x + kvB.y * q0.y + kvB.z * q0.z + kvB.w * q0.w;
        float pB1 = kvB.x * q1.x + kvB.y * q1.y + kvB.z * q1.z + kvB.w * q1.w;
        float pB2 = kvB.x * q2.x + kvB.y * q2.y + kvB.z * q2.z + kvB.w * q2.w;
        float pB3 = kvB.x * q3.x + kvB.y * q3.y + kvB.z * q3.z + kvB.w * q3.w;

        pA0 += __shfl_xor(pA0, 1); pA0 += __shfl_xor(pA0, 2);
        pA1 += __shfl_xor(pA1, 1); pA1 += __shfl_xor(pA1, 2);
        pA2 += __shfl_xor(pA2, 1); pA2 += __shfl_xor(pA2, 2);
        pA3 += __shfl_xor(pA3, 1); pA3 += __shfl_xor(pA3, 2);
        pB0 += __shfl_xor(pB0, 1); pB0 += __shfl_xor(pB0, 2);
        pB1 += __shfl_xor(pB1, 1); pB1 += __shfl_xor(pB1, 2);
        pB2 += __shfl_xor(pB2, 1); pB2 += __shfl_xor(pB2, 2);
        pB3 += __shfl_xor(pB3, 1); pB3 += __shfl_xor(pB3, 2);

        float sA = (qsel & 1) ? ((qsel & 2) ? pA3 : pA1)
                              : ((qsel & 2) ? pA2 : pA0);
        float sB = (qsel & 1) ? ((qsel & 2) ? pB3 : pB1)
                              : ((qsel & 2) ? pB2 : pB0);
        sA += __shfl_xor(sA, 4); sA += __shfl_xor(sA, 8);
        sB += __shfl_xor(sB, 4); sB += __shfl_xor(sB, 8);
        sA *= 0.125f;
        sB = vB ? sB * 0.125f : -INFINITY;

        const float smax = fmaxf(sA, sB);
        if (__any(smax > m_run + 8.f)) {
            const float vmax = wave_max64(smax);
            const float newm = fmaxf(m_run, vmax);
            const float scale = __expf(m_run - newm);
            a0.x *= scale; a0.y *= scale; a0.z *= scale; a0.w *= scale;
            a1.x *= scale; a1.y *= scale; a1.z *= scale; a1.w *= scale;
            a2.x *= scale; a2.y *= scale; a2.z *= scale; a2.w *= scale;
            a3.x *= scale; a3.y *= scale; a3.z *= scale; a3.w *= scale;
            l_run *= scale;
            m_run = newm;
        }
        const float pxA = __expf(sA - m_run);
        const float pxB = __expf(sB - m_run);
        l_run += (cg < 4) ? (pxA + pxB) : 0.f;

        const int srcbase = (sub << 4);
        const float pa0 = __shfl(pxA, srcbase + 0);
        const float pa1 = __shfl(pxA, srcbase + 1);
        const float pa2 = __shfl(pxA, srcbase + 2);
        const float pa3 = __shfl(pxA, srcbase + 3);
        const float pb0 = __shfl(pxB, srcbase + 0);
        const float pb1 = __shfl(pxB, srcbase + 1);
        const float pb2 = __shfl(pxB, srcbase + 2);
        const float pb3 = __shfl(pxB, srcbase + 3);

        a0.x = fmaf(pa0, vvA.x, a0.x); a0.y = fmaf(pa0, vvA.y, a0.y);
        a0.z = fmaf(pa0, vvA.z, a0.z); a0.w = fmaf(pa0, vvA.w, a0.w);
        a1.x = fmaf(pa1, vvA.x, a1.x); a1.y = fmaf(pa1, vvA.y, a1.y);
        a1.z = fmaf(pa1, vvA.z, a1.z); a1.w = fmaf(pa1, vvA.w, a1.w);
        a2.x = fmaf(pa2, vvA.x, a2.x); a2.y = fmaf(pa2, vvA.y, a2.y);
        a2.z = fmaf(pa2, vvA.z, a2.z); a2.w = fmaf(pa2, vvA.w, a2.w);
        a3.x = fmaf(pa3, vvA.x, a3.x); a3.y = fmaf(pa3, vvA.y, a3.y);
        a3.z = fmaf(pa3, vvA.z, a3.z); a3.w = fmaf(pa3, vvA.w, a3.w);

        a0.x = fmaf(pb0, vvB.x, a0.x); a0.y = fmaf(pb0, vvB.y, a0.y);
        a0.z = fmaf(pb0, vvB.z, a0.z); a0.w = fmaf(pb0, vvB.w, a0.w);
        a1.x = fmaf(pb1, vvB.x, a1.x); a1.y = fmaf(pb1, vvB.y, a1.y);
        a1.z = fmaf(pb1, vvB.z, a1.z); a1.w = fmaf(pb1, vvB.w, a1.w);
        a2.x = fmaf(pb2, vvB.x, a2.x); a2.y = fmaf(pb2, vvB.y, a2.y);
        a2.z = fmaf(pb2, vvB.z, a2.z); a2.w = fmaf(pb2, vvB.w, a2.w);
        a3.x = fmaf(pb3, vvB.x, a3.x); a3.y = fmaf(pb3, vvB.y, a3.y);
        a3.z = fmaf(pb3, vvB.z, a3.z); a3.w = fmaf(pb3, vvB.w, a3.w);

        kvA = nkA; vvA = nvA; kvB = nkB; vvB = nvB; vB = vBn;
        r0 = rn;
    }

    a0.x += __shfl_xor(a0.x, 16); a0.x += __shfl_xor(a0.x, 32);
    a0.y += __shfl_xor(a0.y, 16); a0.y += __shfl_xor(a0.y, 32);
    a0.z += __shfl_xor(a0.z, 16); a0.z += __shfl_xor(a0.z, 32);
    a0.w += __shfl_xor(a0.w, 16); a0.w += __shfl_xor(a0.w, 32);
    a1.x += __shfl_xor(a1.x, 16); a1.x += __shfl_xor(a1.x, 32);
    a1.y += __shfl_xor(a1.y, 16); a1.y += __shfl_xor(a1.y, 32);
    a1.z += __shfl_xor(a1.z, 16); a1.z += __shfl_xor(a1.z, 32);
    a1.w += __shfl_xor(a1.w, 16); a1.w += __shfl_xor(a1.w, 32);
    a2.x += __shfl_xor(a2.x, 16); a2.x += __shfl_xor(a2.x, 32);
    a2.y += __shfl_xor(a2.y, 16); a2.y += __shfl_xor(a2.y, 32);
    a2.z += __shfl_xor(a2.z, 16); a2.z += __shfl_xor(a2.z, 32);
    a2.w += __shfl_xor(a2.w, 16); a2.w += __shfl_xor(a2.w, 32);
    a3.x += __shfl_xor(a3.x, 16); a3.x += __shfl_xor(a3.x, 32);
    a3.y += __shfl_xor(a3.y, 16); a3.y += __shfl_xor(a3.y, 32);
    a3.z += __shfl_xor(a3.z, 16); a3.z += __shfl_xor(a3.z, 32);
    a3.w += __shfl_xor(a3.w, 16); a3.w += __shfl_xor(a3.w, 32);

    float l2 = l_run;
    l2 += __shfl_xor(l2, 16); l2 += __shfl_xor(l2, 32);

    if (sub == 0) {
        *(float4*)&ob[wid][0 * 64 + cg * 4] = a0;
        *(float4*)&ob[wid][1 * 64 + cg * 4] = a1;
        *(float4*)&ob[wid][2 * 64 + cg * 4] = a2;
        *(float4*)&ob[wid][3 * 64 + cg * 4] = a3;
    }
    if (lane < 4) lw[wid][lane] = l2;
    if (lane == 0) mw[wid] = m_run;
    __syncthreads();

    const float M = fmaxf(fmaxf(mw[0], mw[1]), fmaxf(mw[2], mw[3]));
    const float w0 = __expf(mw[0] - M), w1 = __expf(mw[1] - M);
    const float w2 = __expf(mw[2] - M), w3 = __expf(mw[3] - M);

    float* rec = part + ((size_t)bh * NC + c) * RECSZ;
    rec[8 + tid] = w0 * ob[0][tid] + w1 * ob[1][tid] +
                   w2 * ob[2][tid] + w3 * ob[3][tid];
    if (tid < 4) {
        rec[tid] = M;
        rec[4 + tid] = w0 * lw[0][tid] + w1 * lw[1][tid] +
                       w2 * lw[2][tid] + w3 * lw[3][tid];
    }
}

// ---------------------------------------------------------------------------
// Fused combine + output projection. grid (32, 16), block 256.
// Block (b, n0): rebuild the combined attention activation for batch b's
// 4 tokens directly from `part` (L2-resident) into LDS, then GEMM vs Wo.
// ---------------------------------------------------------------------------
__global__ __launch_bounds__(256) void combine_proj_out_kernel(
    const float* __restrict__ part, const float* __restrict__ Wo,
    const float* __restrict__ bo, float* __restrict__ out) {
    __shared__ float a_lds[4 * E_];
    __shared__ float res[256];
    __shared__ float wcoef[64][NC + 1];    // [h*4+s][c], padded
    __shared__ float linv[64];
    const int b = blockIdx.x;
    const int n0 = blockIdx.y * 64;
    const int tid = threadIdx.x;

    // phase 1a: per-(h,s) combine weights
    if (tid < 64) {
        const int h = tid >> 2, s = tid & 3;
        const float* base = part + ((size_t)(b * H_ + h) * NC) * RECSZ;
        float m = -1e30f;
        #pragma unroll
        for (int c = 0; c < NC; ++c) m = fmaxf(m, base[c * RECSZ + s]);
        float l = 0.f;
        #pragma unroll
        for (int c = 0; c < NC; ++c) {
            const float w = __expf(base[c * RECSZ + s] - m);
            wcoef[tid][c] = w;
            l = fmaf(base[c * RECSZ + 4 + s], w, l);
        }
        linv[tid] = 1.f / l;
    }
    __syncthreads();

    // phase 1b: a_lds[s][h*64+dk] = sum_c w_c * O_c(s,h,dk) / l
    float4* al4 = (float4*)a_lds;
    #pragma unroll
    for (int i = 0; i < 4; ++i) {
        const int idx = tid + 256 * i;     // float4 slot: s*256 + h*16 + dkg
        const int s = idx >> 8;
        const int rest = idx & 255;
        const int h = rest >> 4, dkg = rest & 15;
        const float* base = part + ((size_t)(b * H_ + h) * NC) * RECSZ
                          + 8 + s * 64 + dkg * 4;
        float4 o = make_float4(0.f, 0.f, 0.f, 0.f);
        #pragma unroll
        for (int c = 0; c < NC; ++c) {
            const float4 v = *(const float4*)(base + c * RECSZ);
            const float w = wcoef[h * 4 + s][c];
            o.x = fmaf(w, v.x, o.x); o.y = fmaf(w, v.y, o.y);
            o.z = fmaf(w, v.z, o.z); o.w = fmaf(w, v.w, o.w);
        }
        const float li = linv[h * 4 + s];
        o.x *= li; o.y *= li; o.z *= li; o.w *= li;
        al4[idx] = o;
    }
    __syncthreads();

    gemm_core(a_lds, Wo, n0, tid, res);
    __syncthreads();

    out[(size_t)(b * 4 + (tid >> 6)) * E_ + n0 + (tid & 63)] =
        res[tid] + bo[n0 + (tid & 63)];
}

// ---------------------------------------------------------------------------
extern "C" void kernel_launch(void* const* d_in, const int* in_sizes, int n_in,
                              void* d_out, int out_size, void* d_ws, size_t ws_size,
                              hipStream_t stream) {
    const float* x  = (const float*)d_in[0];
    const float* ck = (const float*)d_in[1];
    const float* cv = (const float*)d_in[2];
    const float* Wq = (const float*)d_in[3];
    const float* bq = (const float*)d_in[4];
    const float* Wk = (const float*)d_in[5];
    const float* bk = (const float*)d_in[6];
    const float* Wv = (const float*)d_in[7];
    const float* bv = (const float*)d_in[8];
    const float* Wo = (const float*)d_in[9];
    const float* bo = (const float*)d_in[10];
    float* out = (float*)d_out;
    float* ws = (float*)d_ws;

    float* Qw = ws;                           // 131072 floats (z=0)
    float* Kn = ws + 131072;                  // 131072       (z=1)
    float* Vn = ws + 262144;                  // 131072       (z=2)
    float* part = ws + 393216;                // 512*9*264 = 1216512

    hipLaunchKernelGGL(proj_qkv_kernel, dim3(32, 16, 3), dim3(256), 0, stream,
                       x, Wq, bq, Wk, bk, Wv, bv, ws);
    hipLaunchKernelGGL(attn_partial_kernel, dim3(NBH, NC), dim3(256), 0, stream,
                       Qw, ck, cv, Kn, Vn, part);
    hipLaunchKernelGGL(combine_proj_out_kernel, dim3(32, 16), dim3(256), 0, stream,
                       part, Wo, bo, out);
}